// Round 13
// baseline (357.337 us; speedup 1.0000x reference)
//
#include <hip/hip_runtime.h>
#include <hip/hip_cooperative_groups.h>

namespace cg = cooperative_groups;

// Laplacian pyramid, NUM_HIGH=3, img (16,3,512,512) f32, depthwise 5x5 (3,1,5,5).
// reflect-101 input padding; lax.conv = cross-correlation (no flip).
// R13 = R9/R12 level body (bit-identical math, 45.8us plateau) fused into ONE
// cooperative kernel: 1024 blocks x 512 thr (exactly 4 blocks/CU co-resident),
// L0 = 3 marched tiles/block, grid.sync(), L1 (bid<768), grid.sync(), L2 (bid<192).
// Removes 2 inter-kernel gaps (~5-9us of wall time per graph replay).
// Up boundary semantics: down[-1] -> down[1], down[H2] -> down[H2-1] (cols likewise).

#define B_ 16
#define C_ 3
#define DX 64      // down tile width
#define EW 72      // sE/sO padded width (70 used: 140 img cols / 2)
#define SDW 72     // sDn padded width (68 used)
#define DYC 16     // down tile height (all levels in coop kernel)
#define IHC 39     // staged input rows: 2*DYC+7

typedef float f4v __attribute__((ext_vector_type(4)));
typedef float f2v __attribute__((ext_vector_type(2)));

__device__ __forceinline__ int reflect101(int t, int n) {
    t = (t < 0) ? -t : t;
    return (t >= n) ? (2 * n - 2 - t) : t;
}

// One pyramid level on one 64x16 down-tile. Bit-identical to R9/R12.
template<int LOG2HW, bool NTDN>
__device__ __forceinline__ void lap_body(
    const float* __restrict__ in, const float* __restrict__ kern,
    float* __restrict__ down, float* __restrict__ pyr,
    int bc, int dx0, int dy0, int tid,
    float (&sE)[IHC][EW], float (&sO)[IHC][EW], float (&sDn)[DYC + 2][SDW])
{
    constexpr int H  = 1 << LOG2HW, W = H;
    constexpr int H2 = H >> 1,      W2 = W >> 1;

    const int gx0 = 2 * dx0 - 4;
    const int gy0 = 2 * dy0 - 4;

    float kk[25];
    {
        const float* kc = kern + (bc % C_) * 25;
        #pragma unroll
        for (int i = 0; i < 25; ++i) kk[i] = kc[i];
    }

    const float* src = in + (size_t)bc * H * W;   // constexpr stride -> shifts

    // ---------------- stage input tile, de-interleaved ----------------
    {
        const int q  = tid & 31;                  // float4-col 0..31 (img cols 4q..4q+3)
        const int gx = gx0 + 4 * q;
        const bool colOK = (gx >= 0) && (gx + 3 < W);
        const int rb = tid >> 5;                  // 0..15
        const float* p0 = src + (size_t)reflect101(gy0 + rb,       H) * W;
        const float* p1 = src + (size_t)reflect101(gy0 + rb + DYC, H) * W;
        const float* p2 = src + (size_t)reflect101(gy0 + ((rb + 2 * DYC < IHC) ? rb + 2 * DYC : rb), H) * W;
        float4 v0, v1, v2;
        if (colOK) {
            v0 = *(const float4*)(p0 + gx);
            v1 = *(const float4*)(p1 + gx);
            v2 = *(const float4*)(p2 + gx);
        } else {
            const int c0 = reflect101(gx, W), c1 = reflect101(gx + 1, W),
                      c2 = reflect101(gx + 2, W), c3 = reflect101(gx + 3, W);
            v0 = make_float4(p0[c0], p0[c1], p0[c2], p0[c3]);
            v1 = make_float4(p1[c0], p1[c1], p1[c2], p1[c3]);
            v2 = make_float4(p2[c0], p2[c1], p2[c2], p2[c3]);
        }
        *(float2*)&sE[rb][2 * q]       = make_float2(v0.x, v0.z);
        *(float2*)&sO[rb][2 * q]       = make_float2(v0.y, v0.w);
        *(float2*)&sE[rb + DYC][2 * q] = make_float2(v1.x, v1.z);
        *(float2*)&sO[rb + DYC][2 * q] = make_float2(v1.y, v1.w);
        if (rb + 2 * DYC < IHC) {
            *(float2*)&sE[rb + 2 * DYC][2 * q] = make_float2(v2.x, v2.z);
            *(float2*)&sO[rb + 2 * DYC][2 * q] = make_float2(v2.y, v2.w);
        }
        // side float4-cols 32..34 (img cols 128..139), 3-of-4 lanes of tid<4*IHC
        if (tid < 4 * IHC && (tid & 3) < 3) {
            const int r   = tid >> 2;             // 0..IHC-1
            const int q2  = 32 + (tid & 3);
            const int gx2 = gx0 + 4 * q2;
            const float* row = src + (size_t)reflect101(gy0 + r, H) * W;
            float4 v;
            if (gx2 >= 0 && gx2 + 3 < W) v = *(const float4*)(row + gx2);
            else v = make_float4(row[reflect101(gx2, W)], row[reflect101(gx2 + 1, W)],
                                 row[reflect101(gx2 + 2, W)], row[reflect101(gx2 + 3, W)]);
            *(float2*)&sE[r][2 * q2] = make_float2(v.x, v.z);
            *(float2*)&sO[r][2 * q2] = make_float2(v.y, v.w);
        }
    }
    __syncthreads();

    // ---------------- down phase: 4-wide tasks, contiguous E/O reads ----------------
    {
        constexpr int NDM = (DYC + 2) * 16;       // 288 main tasks
        if (tid < NDM + (DYC + 2)) {
            int dr, m0;
            if (tid < NDM) { dr = tid >> 4; m0 = (tid & 15) << 2; }  // m0 = 0,4,..,60
            else           { dr = tid - NDM; m0 = 64; }              // halo cols 64..65
            float o0 = 0.f, o1 = 0.f, o2 = 0.f, o3 = 0.f;
            #pragma unroll
            for (int i = 0; i < 5; ++i) {
                const int r = 2 * dr + i;
                const float4 e0 = *(const float4*)&sE[r][m0];
                const float2 e1 = *(const float2*)&sE[r][m0 + 4];
                const float4 q0 = *(const float4*)&sO[r][m0];
                const float2 q1 = *(const float2*)&sO[r][m0 + 4];
                const float k0 = kk[5*i], k1 = kk[5*i+1], k2 = kk[5*i+2],
                            k3 = kk[5*i+3], k4 = kk[5*i+4];
                o0 += e0.x * k0 + q0.x * k1 + e0.y * k2 + q0.y * k3 + e0.z * k4;
                o1 += e0.y * k0 + q0.y * k1 + e0.z * k2 + q0.z * k3 + e0.w * k4;
                o2 += e0.z * k0 + q0.z * k1 + e0.w * k2 + q0.w * k3 + e1.x * k4;
                o3 += e0.w * k0 + q0.w * k1 + e1.x * k2 + q1.x * k3 + e1.y * k4;
            }
            *(f4v*)&sDn[dr][m0] = (f4v){o0, o1, o2, o3};
        }
    }
    __syncthreads();

    // ---------------- upsub (+ folded down-interior write), 1 task/thread ----------------
    {
        const int pq  = tid & 31;
        const int pr  = tid >> 5;                 // 0..15
        const int gdy = dy0 + pr;
        const int rows0 = (gdy == 0)      ? pr + 2 : pr;       // down[-1] -> down[1]
        const int rows1 = pr + 1;
        const int rows2 = (gdy == H2 - 1) ? pr + 1 : pr + 2;   // down[H2] -> down[H2-1]
        const bool leftE  = (dx0 == 0 && pq == 0);
        const bool rightE = (dx0 + 2 * pq + 1 == W2 - 1);

        float uee_a = 0, ueo_a = 0, uoe_a = 0, uoo_a = 0;
        float uee_b = 0, ueo_b = 0, uoe_b = 0, uoo_b = 0;
        #pragma unroll
        for (int i = 0; i < 3; ++i) {
            const int rr = (i == 0) ? rows0 : (i == 1) ? rows1 : rows2;
            const float2 va = *(const float2*)&sDn[rr][2 * pq];
            const float2 vb = *(const float2*)&sDn[rr][2 * pq + 2];
            float aL = va.x, aC = va.y, aR = vb.x;
            float bL = va.y, bC = vb.x, bR = vb.y;
            if (leftE)  aL = aR;   // down[-1] == down[1]
            if (rightE) bR = bC;   // down[W2] == down[W2-1]
            uee_a += aL * kk[10*i+0] + aC * kk[10*i+2] + aR * kk[10*i+4];
            ueo_a += aC * kk[10*i+1] + aR * kk[10*i+3];
            uee_b += bL * kk[10*i+0] + bC * kk[10*i+2] + bR * kk[10*i+4];
            ueo_b += bC * kk[10*i+1] + bR * kk[10*i+3];
            if (i) {
                uoe_a += aL * kk[10*i-5] + aC * kk[10*i-3] + aR * kk[10*i-1];
                uoo_a += aC * kk[10*i-4] + aR * kk[10*i-2];
                uoe_b += bL * kk[10*i-5] + bC * kk[10*i-3] + bR * kk[10*i-1];
                uoo_b += bC * kk[10*i-4] + bR * kk[10*i-2];
            }
            if (i == 1) {  // center row == down interior: coalesced float2 store
                float* dp = down + (size_t)bc * H2 * W2 + (size_t)gdy * W2 + dx0 + 2 * pq;
                if constexpr (NTDN) __builtin_nontemporal_store((f2v){aC, bC}, (f2v*)dp);
                else                *(float2*)dp = make_float2(aC, bC);
            }
        }

        const int ly = 2 * pr + 4;
        const int u  = 2 * pq + 2;
        const float2 e0 = *(const float2*)&sE[ly][u];
        const float2 q0 = *(const float2*)&sO[ly][u];
        const float2 e1 = *(const float2*)&sE[ly + 1][u];
        const float2 q1 = *(const float2*)&sO[ly + 1][u];

        float* py = pyr + (size_t)bc * H * W;
        const size_t base = (size_t)(2 * gdy) * W + (2 * dx0 + 4 * pq);
        const f4v o0 = {e0.x - uee_a, q0.x - ueo_a, e0.y - uee_b, q0.y - ueo_b};
        const f4v o1 = {e1.x - uoe_a, q1.x - uoo_a, e1.y - uoe_b, q1.y - uoo_b};
        __builtin_nontemporal_store(o0, (f4v*)(py + base));      // pyr is write-once
        __builtin_nontemporal_store(o1, (f4v*)(py + base + W));
    }
}

// ---------------- cooperative fused kernel: all 3 levels ----------------
__global__ __launch_bounds__(512, 8) void lap_coop(
    const float* __restrict__ img, const float* __restrict__ kern,
    float* __restrict__ down1, float* __restrict__ down2,
    float* __restrict__ pyr0, float* __restrict__ pyr1,
    float* __restrict__ pyr2, float* __restrict__ down3)
{
    __shared__ float sE[IHC][EW];
    __shared__ float sO[IHC][EW];
    __shared__ float sDn[DYC + 2][SDW];

    const int tid = threadIdx.x;
    const int bid = blockIdx.x;

    // L0: 3072 tiles (48 bc x 16 yb x 4 xb), 3 marched tiles per block
    #pragma unroll 1
    for (int t = 0; t < 3; ++t) {
        if (t) __syncthreads();               // protect LDS reuse across tiles
        const int tile = bid + t * 1024;
        const int bc   = tile >> 6;           // 64 tiles per bc
        const int rem  = tile & 63;
        const int yb   = rem >> 2;            // 0..15
        const int xb   = rem & 3;             // 0..3
        lap_body<9, false>(img, kern, down1, pyr0, bc, xb * DX, yb * DYC, tid, sE, sO, sDn);
    }
    cg::this_grid().sync();

    // L1: 768 tiles (48 bc x 8 yb x 2 xb)
    if (bid < 768) {
        const int bc  = bid >> 4;
        const int rem = bid & 15;
        const int xb  = rem >> 3;
        const int yb  = rem & 7;
        lap_body<8, false>(down1, kern, down2, pyr1, bc, xb * DX, yb * DYC, tid, sE, sO, sDn);
    }
    cg::this_grid().sync();

    // L2: 192 tiles (48 bc x 4 yb)
    if (bid < 192) {
        const int bc = bid >> 2;
        const int yb = bid & 3;
        lap_body<7, true>(down2, kern, down3, pyr2, bc, 0, yb * DYC, tid, sE, sO, sDn);
    }
}

// ---------------- per-level kernel (R12 path, non-coop fallback) ----------------
template<int LOG2HW, int DY, bool NTST>
__global__ __launch_bounds__(32 * DY, 8) void lap_level_t(
    const float* __restrict__ in, const float* __restrict__ kern,
    float* __restrict__ down, float* __restrict__ pyr)
{
    // Same structure as lap_body but with DY-parameterized shared arrays.
    constexpr int H  = 1 << LOG2HW, W = H;
    constexpr int H2 = H >> 1,      W2 = W >> 1;
    constexpr int IH = 2 * DY + 7;

    __shared__ float sE[IH][EW];
    __shared__ float sO[IH][EW];
    __shared__ float sDn[DY + 2][SDW];

    const int bc  = blockIdx.z;
    const int dx0 = blockIdx.x * DX;
    const int dy0 = blockIdx.y * DY;
    const int gx0 = 2 * dx0 - 4;
    const int gy0 = 2 * dy0 - 4;
    const int tid = threadIdx.x;

    float kk[25];
    {
        const float* kc = kern + (bc % C_) * 25;
        #pragma unroll
        for (int i = 0; i < 25; ++i) kk[i] = kc[i];
    }
    const float* src = in + (size_t)bc * H * W;

    {
        const int q  = tid & 31;
        const int gx = gx0 + 4 * q;
        const bool colOK = (gx >= 0) && (gx + 3 < W);
        const int rb = tid >> 5;
        const float* p0 = src + (size_t)reflect101(gy0 + rb,      H) * W;
        const float* p1 = src + (size_t)reflect101(gy0 + rb + DY, H) * W;
        const float* p2 = src + (size_t)reflect101(gy0 + ((rb + 2 * DY < IH) ? rb + 2 * DY : rb), H) * W;
        float4 v0, v1, v2;
        if (colOK) {
            v0 = *(const float4*)(p0 + gx);
            v1 = *(const float4*)(p1 + gx);
            v2 = *(const float4*)(p2 + gx);
        } else {
            const int c0 = reflect101(gx, W), c1 = reflect101(gx + 1, W),
                      c2 = reflect101(gx + 2, W), c3 = reflect101(gx + 3, W);
            v0 = make_float4(p0[c0], p0[c1], p0[c2], p0[c3]);
            v1 = make_float4(p1[c0], p1[c1], p1[c2], p1[c3]);
            v2 = make_float4(p2[c0], p2[c1], p2[c2], p2[c3]);
        }
        *(float2*)&sE[rb][2 * q]      = make_float2(v0.x, v0.z);
        *(float2*)&sO[rb][2 * q]      = make_float2(v0.y, v0.w);
        *(float2*)&sE[rb + DY][2 * q] = make_float2(v1.x, v1.z);
        *(float2*)&sO[rb + DY][2 * q] = make_float2(v1.y, v1.w);
        if (rb + 2 * DY < IH) {
            *(float2*)&sE[rb + 2 * DY][2 * q] = make_float2(v2.x, v2.z);
            *(float2*)&sO[rb + 2 * DY][2 * q] = make_float2(v2.y, v2.w);
        }
        if (tid < 4 * IH && (tid & 3) < 3) {
            const int r   = tid >> 2;
            const int q2  = 32 + (tid & 3);
            const int gx2 = gx0 + 4 * q2;
            const float* row = src + (size_t)reflect101(gy0 + r, H) * W;
            float4 v;
            if (gx2 >= 0 && gx2 + 3 < W) v = *(const float4*)(row + gx2);
            else v = make_float4(row[reflect101(gx2, W)], row[reflect101(gx2 + 1, W)],
                                 row[reflect101(gx2 + 2, W)], row[reflect101(gx2 + 3, W)]);
            *(float2*)&sE[r][2 * q2] = make_float2(v.x, v.z);
            *(float2*)&sO[r][2 * q2] = make_float2(v.y, v.w);
        }
    }
    __syncthreads();

    {
        constexpr int NDM = (DY + 2) * 16;
        if (tid < NDM + (DY + 2)) {
            int dr, m0;
            if (tid < NDM) { dr = tid >> 4; m0 = (tid & 15) << 2; }
            else           { dr = tid - NDM; m0 = 64; }
            float o0 = 0.f, o1 = 0.f, o2 = 0.f, o3 = 0.f;
            #pragma unroll
            for (int i = 0; i < 5; ++i) {
                const int r = 2 * dr + i;
                const float4 e0 = *(const float4*)&sE[r][m0];
                const float2 e1 = *(const float2*)&sE[r][m0 + 4];
                const float4 q0 = *(const float4*)&sO[r][m0];
                const float2 q1 = *(const float2*)&sO[r][m0 + 4];
                const float k0 = kk[5*i], k1 = kk[5*i+1], k2 = kk[5*i+2],
                            k3 = kk[5*i+3], k4 = kk[5*i+4];
                o0 += e0.x * k0 + q0.x * k1 + e0.y * k2 + q0.y * k3 + e0.z * k4;
                o1 += e0.y * k0 + q0.y * k1 + e0.z * k2 + q0.z * k3 + e0.w * k4;
                o2 += e0.z * k0 + q0.z * k1 + e0.w * k2 + q0.w * k3 + e1.x * k4;
                o3 += e0.w * k0 + q0.w * k1 + e1.x * k2 + q1.x * k3 + e1.y * k4;
            }
            *(f4v*)&sDn[dr][m0] = (f4v){o0, o1, o2, o3};
        }
    }
    __syncthreads();

    {
        const int pq  = tid & 31;
        const int pr  = tid >> 5;
        const int gdy = dy0 + pr;
        const int rows0 = (gdy == 0)      ? pr + 2 : pr;
        const int rows1 = pr + 1;
        const int rows2 = (gdy == H2 - 1) ? pr + 1 : pr + 2;
        const bool leftE  = (dx0 == 0 && pq == 0);
        const bool rightE = (dx0 + 2 * pq + 1 == W2 - 1);

        float uee_a = 0, ueo_a = 0, uoe_a = 0, uoo_a = 0;
        float uee_b = 0, ueo_b = 0, uoe_b = 0, uoo_b = 0;
        #pragma unroll
        for (int i = 0; i < 3; ++i) {
            const int rr = (i == 0) ? rows0 : (i == 1) ? rows1 : rows2;
            const float2 va = *(const float2*)&sDn[rr][2 * pq];
            const float2 vb = *(const float2*)&sDn[rr][2 * pq + 2];
            float aL = va.x, aC = va.y, aR = vb.x;
            float bL = va.y, bC = vb.x, bR = vb.y;
            if (leftE)  aL = aR;
            if (rightE) bR = bC;
            uee_a += aL * kk[10*i+0] + aC * kk[10*i+2] + aR * kk[10*i+4];
            ueo_a += aC * kk[10*i+1] + aR * kk[10*i+3];
            uee_b += bL * kk[10*i+0] + bC * kk[10*i+2] + bR * kk[10*i+4];
            ueo_b += bC * kk[10*i+1] + bR * kk[10*i+3];
            if (i) {
                uoe_a += aL * kk[10*i-5] + aC * kk[10*i-3] + aR * kk[10*i-1];
                uoo_a += aC * kk[10*i-4] + aR * kk[10*i-2];
                uoe_b += bL * kk[10*i-5] + bC * kk[10*i-3] + bR * kk[10*i-1];
                uoo_b += bC * kk[10*i-4] + bR * kk[10*i-2];
            }
            if (i == 1) {
                float* dp = down + (size_t)bc * H2 * W2 + (size_t)gdy * W2 + dx0 + 2 * pq;
                if constexpr (NTST) __builtin_nontemporal_store((f2v){aC, bC}, (f2v*)dp);
                else                *(float2*)dp = make_float2(aC, bC);
            }
        }

        const int ly = 2 * pr + 4;
        const int u  = 2 * pq + 2;
        const float2 e0 = *(const float2*)&sE[ly][u];
        const float2 q0 = *(const float2*)&sO[ly][u];
        const float2 e1 = *(const float2*)&sE[ly + 1][u];
        const float2 q1 = *(const float2*)&sO[ly + 1][u];

        float* py = pyr + (size_t)bc * H * W;
        const size_t base = (size_t)(2 * gdy) * W + (2 * dx0 + 4 * pq);
        const f4v o0 = {e0.x - uee_a, q0.x - ueo_a, e0.y - uee_b, q0.y - ueo_b};
        const f4v o1 = {e1.x - uoe_a, q1.x - uoo_a, e1.y - uoe_b, q1.y - uoo_b};
        __builtin_nontemporal_store(o0, (f4v*)(py + base));
        __builtin_nontemporal_store(o1, (f4v*)(py + base + W));
    }
}

// ---------------- fallback (no-workspace) kernels ----------------
__global__ __launch_bounds__(256) void down_kernel(
    const float* __restrict__ in, const float* __restrict__ kern,
    float* __restrict__ out, int H, int W)
{
    const int H2 = H >> 1, W2 = W >> 1;
    const int bc = blockIdx.z;
    const int c  = bc % C_;
    __shared__ float k[25];
    int tid = threadIdx.y * blockDim.x + threadIdx.x;
    if (tid < 25) k[tid] = kern[c * 25 + tid];
    __syncthreads();
    int x = blockIdx.x * blockDim.x + threadIdx.x;
    int y = blockIdx.y * blockDim.y + threadIdx.y;
    if (x >= W2 || y >= H2) return;
    const float* img = in + (size_t)bc * H * W;
    const int bx = 2 * x - 2, by = 2 * y - 2;
    float acc = 0.f;
    if (bx >= 0 && by >= 0 && bx + 4 < W && by + 4 < H) {
        const float* p = img + (size_t)by * W + bx;
        #pragma unroll
        for (int dy = 0; dy < 5; ++dy) {
            #pragma unroll
            for (int dx = 0; dx < 5; ++dx) acc += p[dx] * k[dy * 5 + dx];
            p += W;
        }
    } else {
        #pragma unroll
        for (int dy = 0; dy < 5; ++dy) {
            const float* row = img + (size_t)reflect101(by + dy, H) * W;
            #pragma unroll
            for (int dx = 0; dx < 5; ++dx) acc += row[reflect101(bx + dx, W)] * k[dy * 5 + dx];
        }
    }
    out[(size_t)bc * H2 * W2 + (size_t)y * W2 + x] = acc;
}

__global__ __launch_bounds__(256) void upsub_kernel(
    const float* __restrict__ cur, const float* __restrict__ kern,
    const float* __restrict__ down, float* __restrict__ pyr,
    int H2, int W2)
{
    const int H = H2 * 2, W = W2 * 2;
    const int bc = blockIdx.z;
    const int c  = bc % C_;
    __shared__ float k[25];
    int tid = threadIdx.y * blockDim.x + threadIdx.x;
    if (tid < 25) k[tid] = kern[c * 25 + tid];
    __syncthreads();
    int x2 = blockIdx.x * blockDim.x + threadIdx.x;
    int y2 = blockIdx.y * blockDim.y + threadIdx.y;
    if (x2 >= W2 || y2 >= H2) return;
    const float* dn = down + (size_t)bc * H2 * W2;
    const float* cu = cur  + (size_t)bc * H * W;
    float*       py = pyr  + (size_t)bc * H * W;
    const int xm = (x2 == 0)      ? 1      : x2 - 1;
    const int xp = (x2 == W2 - 1) ? W2 - 1 : x2 + 1;
    const int ym = (y2 == 0)      ? 1      : y2 - 1;
    const int yp = (y2 == H2 - 1) ? H2 - 1 : y2 + 1;
    float d[3][3];
    {
        const float* r0 = dn + (size_t)ym * W2;
        const float* r1 = dn + (size_t)y2 * W2;
        const float* r2 = dn + (size_t)yp * W2;
        d[0][0] = r0[xm]; d[0][1] = r0[x2]; d[0][2] = r0[xp];
        d[1][0] = r1[xm]; d[1][1] = r1[x2]; d[1][2] = r1[xp];
        d[2][0] = r2[xm]; d[2][1] = r2[x2]; d[2][2] = r2[xp];
    }
    float uee = 0.f, ueo = 0.f, uoe = 0.f, uoo = 0.f;
    #pragma unroll
    for (int i = 0; i < 3; ++i) {
        #pragma unroll
        for (int j = 0; j < 3; ++j) {
            const float v = d[i][j];
            uee += v * k[(2 * i) * 5 + 2 * j];
            if (j)      ueo += v * k[(2 * i) * 5 + 2 * j - 1];
            if (i)      uoe += v * k[(2 * i - 1) * 5 + 2 * j];
            if (i && j) uoo += v * k[(2 * i - 1) * 5 + 2 * j - 1];
        }
    }
    const int y = 2 * y2, x = 2 * x2;
    const float2 c0 = *(const float2*)(cu + (size_t)y       * W + x);
    const float2 c1 = *(const float2*)(cu + (size_t)(y + 1) * W + x);
    *(float2*)(py + (size_t)y       * W + x) = make_float2(c0.x - uee, c0.y - ueo);
    *(float2*)(py + (size_t)(y + 1) * W + x) = make_float2(c1.x - uoe, c1.y - uoo);
}

extern "C" void kernel_launch(void* const* d_in, const int* in_sizes, int n_in,
                              void* d_out, int out_size, void* d_ws, size_t ws_size,
                              hipStream_t stream) {
    const float* img  = (const float*)d_in[0];
    const float* kern = (const float*)d_in[1];
    float* out = (float*)d_out;

    const size_t n0 = (size_t)B_ * C_ * 512 * 512;
    const size_t n1 = (size_t)B_ * C_ * 256 * 256;
    const size_t n2 = (size_t)B_ * C_ * 128 * 128;

    float* pyr0  = out;
    float* pyr1  = out + n0;
    float* pyr2  = out + n0 + n1;
    float* down3 = out + n0 + n1 + n2;

    const int BC = B_ * C_;
    const size_t need = (n1 + n2) * sizeof(float);

    if (ws_size >= need) {
        float* down1 = (float*)d_ws;
        float* down2 = down1 + n1;

        int dev = 0, coopOK = 0;
        hipGetDevice(&dev);
        hipDeviceGetAttribute(&coopOK, hipDeviceAttributeCooperativeLaunch, dev);

        bool launched = false;
        if (coopOK) {
            void* args[8] = { (void*)&img, (void*)&kern, (void*)&down1, (void*)&down2,
                              (void*)&pyr0, (void*)&pyr1, (void*)&pyr2, (void*)&down3 };
            hipError_t e = hipLaunchCooperativeKernel((void*)lap_coop, dim3(1024), dim3(512),
                                                      args, 0, stream);
            launched = (e == hipSuccess);
        }
        if (!launched) {
            // proven R12 3-kernel path
            lap_level_t<9, 16, false><<<dim3(256 / DX, 256 / 16, BC), 512, 0, stream>>>(img,   kern, down1, pyr0);
            lap_level_t<8,  8, false><<<dim3(128 / DX, 128 /  8, BC), 256, 0, stream>>>(down1, kern, down2, pyr1);
            lap_level_t<7,  8, true ><<<dim3( 64 / DX,  64 /  8, BC), 256, 0, stream>>>(down2, kern, down3, pyr2);
        }
    } else {
        float* down1 = pyr1;
        float* down2 = pyr2;
        const dim3 blk(64, 4, 1);
        auto g2 = [&](int W2, int H2) { return dim3((W2 + 63) / 64, (H2 + 3) / 4, BC); };
        down_kernel <<<g2(256, 256), blk, 0, stream>>>(img, kern, down1, 512, 512);
        upsub_kernel<<<g2(256, 256), blk, 0, stream>>>(img, kern, down1, pyr0, 256, 256);
        down_kernel <<<g2(128, 128), blk, 0, stream>>>(down1, kern, down2, 256, 256);
        upsub_kernel<<<g2(128, 128), blk, 0, stream>>>(down1, kern, down2, pyr1, 128, 128);
        down_kernel <<<g2( 64,  64), blk, 0, stream>>>(down2, kern, down3, 128, 128);
        upsub_kernel<<<g2( 64,  64), blk, 0, stream>>>(down2, kern, down3, pyr2, 64, 64);
    }
}

// Round 14
// 44.762 us; speedup vs baseline: 7.9830x; 7.9830x over previous
//
#include <hip/hip_runtime.h>

// Laplacian pyramid, NUM_HIGH=3, img (16,3,512,512) f32, depthwise 5x5 (3,1,5,5).
// reflect-101 input padding; lax.conv = cross-correlation (no flip).
// R14 = R12 (proven best 45.8us) + XCD-aware bijective block swizzle on L0:
// L0 grid flattened to 1D(768); swz=(bid%8)*96+bid/8 gives each XCD a contiguous
// 96-tile run (~1.5 images) so neighbor-tile staging halos are co-XCD L2 hits.
// Up boundary semantics: down[-1] -> down[1], down[H2] -> down[H2-1] (cols likewise).

#define B_ 16
#define C_ 3
#define DX 64      // down tile width (all levels)
#define EW 72      // sE/sO padded width (70 used: 140 img cols / 2)
#define SDW 72     // sDn padded width (68 used)

typedef float f4v __attribute__((ext_vector_type(4)));
typedef float f2v __attribute__((ext_vector_type(2)));

__device__ __forceinline__ int reflect101(int t, int n) {
    t = (t < 0) ? -t : t;
    return (t >= n) ? (2 * n - 2 - t) : t;
}

// SWZ=0: 3D grid (x=xb, y=yb, z=bc). SWZ=1: 1D grid, XCD-swizzled (L0 only).
template<int LOG2HW, int DY, bool NTST, int SWZ, int NXB, int NYB>
__global__ __launch_bounds__(32 * DY, 8) void lap_level_t(
    const float* __restrict__ in, const float* __restrict__ kern,
    float* __restrict__ down, float* __restrict__ pyr)
{
    constexpr int H  = 1 << LOG2HW, W = H;
    constexpr int H2 = H >> 1,      W2 = W >> 1;
    constexpr int IH = 2 * DY + 7;            // staged input rows

    __shared__ float sE[IH][EW];              // even img cols of tile (col 2u)
    __shared__ float sO[IH][EW];              // odd  img cols of tile (col 2u+1)
    __shared__ float sDn[DY + 2][SDW];        // sDn[r][j] = down[dy0-1+r][dx0-1+j]

    int bc, dx0, dy0;
    if constexpr (SWZ) {
        constexpr int NWG = NXB * NYB * B_ * C_;
        constexpr int CPX = NWG / 8;          // tiles per XCD chunk (NWG % 8 == 0)
        const int bid = blockIdx.x;
        const int swz = (bid & 7) * CPX + (bid >> 3);
        dx0 = (swz % NXB) * DX;
        dy0 = ((swz / NXB) % NYB) * DY;
        bc  = swz / (NXB * NYB);
    } else {
        bc  = blockIdx.z;
        dx0 = blockIdx.x * DX;
        dy0 = blockIdx.y * DY;
    }
    const int gx0 = 2 * dx0 - 4;
    const int gy0 = 2 * dy0 - 4;
    const int tid = threadIdx.x;

    // taps: block-uniform -> scalar loads
    float kk[25];
    {
        const float* kc = kern + (bc % C_) * 25;
        #pragma unroll
        for (int i = 0; i < 25; ++i) kk[i] = kc[i];
    }

    const float* src = in + (size_t)bc * H * W;   // constexpr stride -> shifts

    // ---------------- stage input tile, de-interleaved (R5 layout) ----------------
    {
        const int q  = tid & 31;                  // float4-col 0..31 (img cols 4q..4q+3)
        const int gx = gx0 + 4 * q;
        const bool colOK = (gx >= 0) && (gx + 3 < W);
        const int rb = tid >> 5;                  // 0..DY-1
        const float* p0 = src + (size_t)reflect101(gy0 + rb,      H) * W;
        const float* p1 = src + (size_t)reflect101(gy0 + rb + DY, H) * W;
        const float* p2 = src + (size_t)reflect101(gy0 + ((rb + 2 * DY < IH) ? rb + 2 * DY : rb), H) * W;
        float4 v0, v1, v2;
        if (colOK) {
            v0 = *(const float4*)(p0 + gx);
            v1 = *(const float4*)(p1 + gx);
            v2 = *(const float4*)(p2 + gx);
        } else {
            const int c0 = reflect101(gx, W), c1 = reflect101(gx + 1, W),
                      c2 = reflect101(gx + 2, W), c3 = reflect101(gx + 3, W);
            v0 = make_float4(p0[c0], p0[c1], p0[c2], p0[c3]);
            v1 = make_float4(p1[c0], p1[c1], p1[c2], p1[c3]);
            v2 = make_float4(p2[c0], p2[c1], p2[c2], p2[c3]);
        }
        *(float2*)&sE[rb][2 * q]      = make_float2(v0.x, v0.z);
        *(float2*)&sO[rb][2 * q]      = make_float2(v0.y, v0.w);
        *(float2*)&sE[rb + DY][2 * q] = make_float2(v1.x, v1.z);
        *(float2*)&sO[rb + DY][2 * q] = make_float2(v1.y, v1.w);
        if (rb + 2 * DY < IH) {
            *(float2*)&sE[rb + 2 * DY][2 * q] = make_float2(v2.x, v2.z);
            *(float2*)&sO[rb + 2 * DY][2 * q] = make_float2(v2.y, v2.w);
        }
        // side float4-cols 32..34 (img cols 128..139), 3-of-4 lanes of tid<4*IH
        if (tid < 4 * IH && (tid & 3) < 3) {
            const int r   = tid >> 2;             // 0..IH-1
            const int q2  = 32 + (tid & 3);
            const int gx2 = gx0 + 4 * q2;
            const float* row = src + (size_t)reflect101(gy0 + r, H) * W;
            float4 v;
            if (gx2 >= 0 && gx2 + 3 < W) v = *(const float4*)(row + gx2);
            else v = make_float4(row[reflect101(gx2, W)], row[reflect101(gx2 + 1, W)],
                                 row[reflect101(gx2 + 2, W)], row[reflect101(gx2 + 3, W)]);
            *(float2*)&sE[r][2 * q2] = make_float2(v.x, v.z);
            *(float2*)&sO[r][2 * q2] = make_float2(v.y, v.w);
        }
    }
    __syncthreads();

    // ---------------- down phase: 4-wide tasks, contiguous E/O reads ----------------
    // sDn[dr][m] = sum_i k0*E[m] + k1*O[m] + k2*E[m+1] + k3*O[m+1] + k4*E[m+2] (rows 2dr+i)
    {
        constexpr int NDM = (DY + 2) * 16;        // main tasks (pow2 per row)
        if (tid < NDM + (DY + 2)) {
            int dr, m0;
            if (tid < NDM) { dr = tid >> 4; m0 = (tid & 15) << 2; }  // m0 = 0,4,..,60
            else           { dr = tid - NDM; m0 = 64; }              // halo cols 64..65
            float o0 = 0.f, o1 = 0.f, o2 = 0.f, o3 = 0.f;
            #pragma unroll
            for (int i = 0; i < 5; ++i) {
                const int r = 2 * dr + i;
                const float4 e0 = *(const float4*)&sE[r][m0];
                const float2 e1 = *(const float2*)&sE[r][m0 + 4];
                const float4 q0 = *(const float4*)&sO[r][m0];
                const float2 q1 = *(const float2*)&sO[r][m0 + 4];
                const float k0 = kk[5*i], k1 = kk[5*i+1], k2 = kk[5*i+2],
                            k3 = kk[5*i+3], k4 = kk[5*i+4];
                o0 += e0.x * k0 + q0.x * k1 + e0.y * k2 + q0.y * k3 + e0.z * k4;
                o1 += e0.y * k0 + q0.y * k1 + e0.z * k2 + q0.z * k3 + e0.w * k4;
                o2 += e0.z * k0 + q0.z * k1 + e0.w * k2 + q0.w * k3 + e1.x * k4;
                o3 += e0.w * k0 + q0.w * k1 + e1.x * k2 + q1.x * k3 + e1.y * k4;
            }
            *(f4v*)&sDn[dr][m0] = (f4v){o0, o1, o2, o3};
        }
    }
    __syncthreads();

    // ---------------- upsub (+ folded down-interior write), 1 task/thread ----------------
    {
        const int pq  = tid & 31;
        const int pr  = tid >> 5;                 // 0..DY-1
        const int gdy = dy0 + pr;
        // sDn row pr = down[gdy-1], pr+1 = down[gdy], pr+2 = down[gdy+1]
        const int rows0 = (gdy == 0)      ? pr + 2 : pr;       // top: down[-1] -> down[1]
        const int rows1 = pr + 1;
        const int rows2 = (gdy == H2 - 1) ? pr + 1 : pr + 2;   // bottom: down[H2] -> down[H2-1]
        const bool leftE  = (dx0 == 0 && pq == 0);
        const bool rightE = (dx0 + 2 * pq + 1 == W2 - 1);

        float uee_a = 0, ueo_a = 0, uoe_a = 0, uoo_a = 0;
        float uee_b = 0, ueo_b = 0, uoe_b = 0, uoo_b = 0;
        #pragma unroll
        for (int i = 0; i < 3; ++i) {
            const int rr = (i == 0) ? rows0 : (i == 1) ? rows1 : rows2;
            const float2 va = *(const float2*)&sDn[rr][2 * pq];
            const float2 vb = *(const float2*)&sDn[rr][2 * pq + 2];
            float aL = va.x, aC = va.y, aR = vb.x;
            float bL = va.y, bC = vb.x, bR = vb.y;
            if (leftE)  aL = aR;   // down[-1] == down[1]
            if (rightE) bR = bC;   // down[W2] == down[W2-1]
            uee_a += aL * kk[10*i+0] + aC * kk[10*i+2] + aR * kk[10*i+4];
            ueo_a += aC * kk[10*i+1] + aR * kk[10*i+3];
            uee_b += bL * kk[10*i+0] + bC * kk[10*i+2] + bR * kk[10*i+4];
            ueo_b += bC * kk[10*i+1] + bR * kk[10*i+3];
            if (i) {
                uoe_a += aL * kk[10*i-5] + aC * kk[10*i-3] + aR * kk[10*i-1];
                uoo_a += aC * kk[10*i-4] + aR * kk[10*i-2];
                uoe_b += bL * kk[10*i-5] + bC * kk[10*i-3] + bR * kk[10*i-1];
                uoo_b += bC * kk[10*i-4] + bR * kk[10*i-2];
            }
            if (i == 1) {  // center row == down interior: coalesced float2 store
                float* dp = down + (size_t)bc * H2 * W2 + (size_t)gdy * W2 + dx0 + 2 * pq;
                if constexpr (NTST) __builtin_nontemporal_store((f2v){aC, bC}, (f2v*)dp);
                else                *(float2*)dp = make_float2(aC, bC);
            }
        }

        // cur 2x4 block from de-interleaved tile: img rows 2gdy(+1), cols 4pq+4..4pq+7
        const int ly = 2 * pr + 4;
        const int u  = 2 * pq + 2;
        const float2 e0 = *(const float2*)&sE[ly][u];
        const float2 q0 = *(const float2*)&sO[ly][u];
        const float2 e1 = *(const float2*)&sE[ly + 1][u];
        const float2 q1 = *(const float2*)&sO[ly + 1][u];

        float* py = pyr + (size_t)bc * H * W;
        const size_t base = (size_t)(2 * gdy) * W + (2 * dx0 + 4 * pq);
        const f4v o0 = {e0.x - uee_a, q0.x - ueo_a, e0.y - uee_b, q0.y - ueo_b};
        const f4v o1 = {e1.x - uoe_a, q1.x - uoo_a, e1.y - uoe_b, q1.y - uoo_b};
        __builtin_nontemporal_store(o0, (f4v*)(py + base));      // pyr is write-once
        __builtin_nontemporal_store(o1, (f4v*)(py + base + W));
    }
}

// ---------------- fallback (no-workspace) kernels (R1, correct boundaries) ----------------
__global__ __launch_bounds__(256) void down_kernel(
    const float* __restrict__ in, const float* __restrict__ kern,
    float* __restrict__ out, int H, int W)
{
    const int H2 = H >> 1, W2 = W >> 1;
    const int bc = blockIdx.z;
    const int c  = bc % C_;
    __shared__ float k[25];
    int tid = threadIdx.y * blockDim.x + threadIdx.x;
    if (tid < 25) k[tid] = kern[c * 25 + tid];
    __syncthreads();
    int x = blockIdx.x * blockDim.x + threadIdx.x;
    int y = blockIdx.y * blockDim.y + threadIdx.y;
    if (x >= W2 || y >= H2) return;
    const float* img = in + (size_t)bc * H * W;
    const int bx = 2 * x - 2, by = 2 * y - 2;
    float acc = 0.f;
    if (bx >= 0 && by >= 0 && bx + 4 < W && by + 4 < H) {
        const float* p = img + (size_t)by * W + bx;
        #pragma unroll
        for (int dy = 0; dy < 5; ++dy) {
            #pragma unroll
            for (int dx = 0; dx < 5; ++dx) acc += p[dx] * k[dy * 5 + dx];
            p += W;
        }
    } else {
        #pragma unroll
        for (int dy = 0; dy < 5; ++dy) {
            const float* row = img + (size_t)reflect101(by + dy, H) * W;
            #pragma unroll
            for (int dx = 0; dx < 5; ++dx) acc += row[reflect101(bx + dx, W)] * k[dy * 5 + dx];
        }
    }
    out[(size_t)bc * H2 * W2 + (size_t)y * W2 + x] = acc;
}

__global__ __launch_bounds__(256) void upsub_kernel(
    const float* __restrict__ cur, const float* __restrict__ kern,
    const float* __restrict__ down, float* __restrict__ pyr,
    int H2, int W2)
{
    const int H = H2 * 2, W = W2 * 2;
    const int bc = blockIdx.z;
    const int c  = bc % C_;
    __shared__ float k[25];
    int tid = threadIdx.y * blockDim.x + threadIdx.x;
    if (tid < 25) k[tid] = kern[c * 25 + tid];
    __syncthreads();
    int x2 = blockIdx.x * blockDim.x + threadIdx.x;
    int y2 = blockIdx.y * blockDim.y + threadIdx.y;
    if (x2 >= W2 || y2 >= H2) return;
    const float* dn = down + (size_t)bc * H2 * W2;
    const float* cu = cur  + (size_t)bc * H * W;
    float*       py = pyr  + (size_t)bc * H * W;
    const int xm = (x2 == 0)      ? 1      : x2 - 1;
    const int xp = (x2 == W2 - 1) ? W2 - 1 : x2 + 1;
    const int ym = (y2 == 0)      ? 1      : y2 - 1;
    const int yp = (y2 == H2 - 1) ? H2 - 1 : y2 + 1;
    float d[3][3];
    {
        const float* r0 = dn + (size_t)ym * W2;
        const float* r1 = dn + (size_t)y2 * W2;
        const float* r2 = dn + (size_t)yp * W2;
        d[0][0] = r0[xm]; d[0][1] = r0[x2]; d[0][2] = r0[xp];
        d[1][0] = r1[xm]; d[1][1] = r1[x2]; d[1][2] = r1[xp];
        d[2][0] = r2[xm]; d[2][1] = r2[x2]; d[2][2] = r2[xp];
    }
    float uee = 0.f, ueo = 0.f, uoe = 0.f, uoo = 0.f;
    #pragma unroll
    for (int i = 0; i < 3; ++i) {
        #pragma unroll
        for (int j = 0; j < 3; ++j) {
            const float v = d[i][j];
            uee += v * k[(2 * i) * 5 + 2 * j];
            if (j)      ueo += v * k[(2 * i) * 5 + 2 * j - 1];
            if (i)      uoe += v * k[(2 * i - 1) * 5 + 2 * j];
            if (i && j) uoo += v * k[(2 * i - 1) * 5 + 2 * j - 1];
        }
    }
    const int y = 2 * y2, x = 2 * x2;
    const float2 c0 = *(const float2*)(cu + (size_t)y       * W + x);
    const float2 c1 = *(const float2*)(cu + (size_t)(y + 1) * W + x);
    *(float2*)(py + (size_t)y       * W + x) = make_float2(c0.x - uee, c0.y - ueo);
    *(float2*)(py + (size_t)(y + 1) * W + x) = make_float2(c1.x - uoe, c1.y - uoo);
}

extern "C" void kernel_launch(void* const* d_in, const int* in_sizes, int n_in,
                              void* d_out, int out_size, void* d_ws, size_t ws_size,
                              hipStream_t stream) {
    const float* img  = (const float*)d_in[0];
    const float* kern = (const float*)d_in[1];
    float* out = (float*)d_out;

    const size_t n0 = (size_t)B_ * C_ * 512 * 512;
    const size_t n1 = (size_t)B_ * C_ * 256 * 256;
    const size_t n2 = (size_t)B_ * C_ * 128 * 128;

    float* pyr0  = out;
    float* pyr1  = out + n0;
    float* pyr2  = out + n0 + n1;
    float* down3 = out + n0 + n1 + n2;

    const int BC = B_ * C_;
    const size_t need = (n1 + n2) * sizeof(float);

    if (ws_size >= need) {
        float* down1 = (float*)d_ws;
        float* down2 = down1 + n1;
        // L0: 512 -> 256, DY=16 @ 512 threads, 1D XCD-swizzled grid (768 = 8 x 96)
        lap_level_t<9, 16, false, 1, 4, 16><<<dim3(4 * 16 * B_ * C_), 512, 0, stream>>>(img,   kern, down1, pyr0);
        // L1: 256 -> 128, DY=8 @ 256 threads (R12 config)
        lap_level_t<8,  8, false, 0, 2, 16><<<dim3(128 / DX, 128 /  8, BC), 256, 0, stream>>>(down1, kern, down2, pyr1);
        // L2: 128 -> 64, DY=8 @ 256 threads (down3 final: NT store)
        lap_level_t<7,  8, true,  0, 1,  8><<<dim3( 64 / DX,  64 /  8, BC), 256, 0, stream>>>(down2, kern, down3, pyr2);
    } else {
        float* down1 = pyr1;
        float* down2 = pyr2;
        const dim3 blk(64, 4, 1);
        auto g2 = [&](int W2, int H2) { return dim3((W2 + 63) / 64, (H2 + 3) / 4, BC); };
        down_kernel <<<g2(256, 256), blk, 0, stream>>>(img, kern, down1, 512, 512);
        upsub_kernel<<<g2(256, 256), blk, 0, stream>>>(img, kern, down1, pyr0, 256, 256);
        down_kernel <<<g2(128, 128), blk, 0, stream>>>(down1, kern, down2, 256, 256);
        upsub_kernel<<<g2(128, 128), blk, 0, stream>>>(down1, kern, down2, pyr1, 128, 128);
        down_kernel <<<g2( 64,  64), blk, 0, stream>>>(down2, kern, down3, 128, 128);
        upsub_kernel<<<g2( 64,  64), blk, 0, stream>>>(down2, kern, down3, pyr2, 64, 64);
    }
}